// Round 8
// baseline (782.087 us; speedup 1.0000x reference)
//
#include <hip/hip_runtime.h>
#include <hip/hip_bf16.h>

#define NN 30000
#define NE 960000
#define HID 128
#define NL 3
#define NB 64
#define BN_EPS 1e-5f
#define LEAKY 0.2f

// ---------------- workspace layout (float elements) ----------------
#define OFF_CNT      0
#define OFF_FILL     (OFF_CNT + NN)
#define OFF_BNSTATS  (OFF_FILL + NN)
#define ZERO_ELEMS   (OFF_BNSTATS + 3*256)
#define OFF_ROWSTART (ZERO_ELEMS)                    // NN+1 ints (pad 30016)
#define OFF_WE3      (OFF_ROWSTART + 30016)          // 3*4*128 floats
#define OFF_H        (OFF_WE3 + 1536)
#define OFF_XLB      (OFF_H  + NN*HID)               // bf16 [NN][128]
#define OFF_XR       (OFF_XLB + NN*HID/2)
#define OFF_G        (OFF_XR + NN*HID)
#define OFF_CSR      (OFF_G  + NN*HID)               // NE float4
#define OFF_C1       (OFF_CSR + NE*4)                // 64*256
#define OFF_C2       (OFF_C1 + 64*256)               // 64*128

#define LD8(dst, ptr) { float4 a_ = *(const float4*)(ptr); float4 b_ = *(const float4*)((ptr)+4); \
    dst[0]=a_.x; dst[1]=a_.y; dst[2]=a_.z; dst[3]=a_.w; dst[4]=b_.x; dst[5]=b_.y; dst[6]=b_.z; dst[7]=b_.w; }

// load 8 bf16 (16 B) and widen to fp32
#define LDBF8(dst, ptr) { uint4 t_ = *(const uint4*)(ptr); \
    dst[0]=__uint_as_float(t_.x<<16); dst[1]=__uint_as_float(t_.x&0xffff0000u); \
    dst[2]=__uint_as_float(t_.y<<16); dst[3]=__uint_as_float(t_.y&0xffff0000u); \
    dst[4]=__uint_as_float(t_.z<<16); dst[5]=__uint_as_float(t_.z&0xffff0000u); \
    dst[6]=__uint_as_float(t_.w<<16); dst[7]=__uint_as_float(t_.w&0xffff0000u); }

__device__ __forceinline__ unsigned f2bf(float f) { // round-to-nearest-even
    unsigned u = __float_as_uint(f);
    return (u + 0x7fffu + ((u >> 16) & 1u)) >> 16;
}

// ---------------- We3[l] = epW @ We[l], web[l] = epB @ We[l] ----------------
__global__ void k_prep_we3(const float* __restrict__ epW, const float* __restrict__ epB,
                           const float* __restrict__ We, float* __restrict__ we3web) {
    int idx = blockIdx.x * 256 + threadIdx.x;
    if (idx >= 3 * 512) return;
    int l = idx / 512, rem = idx % 512;
    int r = rem / 128, j = rem % 128;
    const float* W = We + l * HID * HID;
    float acc = 0.f;
    if (r < 3) {
        for (int c = 0; c < HID; ++c) acc = fmaf(epW[r * HID + c], W[c * HID + j], acc);
    } else {
        for (int c = 0; c < HID; ++c) acc = fmaf(epB[c], W[c * HID + j], acc);
    }
    we3web[l * 512 + r * 128 + j] = acc;
}

// ---------------- histogram ----------------
__global__ void k_hist(const int* __restrict__ ei, int* __restrict__ cnt) {
    int e = blockIdx.x * 256 + threadIdx.x;
    if (e >= NE) return;
    atomicAdd(&cnt[ei[NE + e]], 1);
}

// ---------------- exclusive scan ----------------
__global__ __launch_bounds__(1024) void k_scan(const int* __restrict__ cnt, int* __restrict__ rowstart) {
    __shared__ int s[1024];
    const int CH = 30;
    int t = threadIdx.x;
    int base = t * CH;
    int loc[CH];
    int sum = 0;
    #pragma unroll
    for (int i = 0; i < CH; ++i) {
        int idx = base + i;
        int v = (idx < NN) ? cnt[idx] : 0;
        loc[i] = sum;
        sum += v;
    }
    s[t] = sum;
    __syncthreads();
    for (int off = 1; off < 1024; off <<= 1) {
        int x = (t >= off) ? s[t - off] : 0;
        __syncthreads();
        s[t] += x;
        __syncthreads();
    }
    int carry = (t > 0) ? s[t - 1] : 0;
    #pragma unroll
    for (int i = 0; i < CH; ++i) {
        int idx = base + i;
        if (idx < NN) rowstart[idx] = carry + loc[i];
    }
    if (t == 1023) rowstart[NN] = s[1023];
}

// ---------------- scatter edges into CSR ----------------
__global__ void k_scatter(const int* __restrict__ ei, const float* __restrict__ ea,
                          const int* __restrict__ rowstart, int* __restrict__ fill,
                          float4* __restrict__ csr) {
    int e = blockIdx.x * 256 + threadIdx.x;
    if (e >= NE) return;
    int d = ei[NE + e];
    int pos = rowstart[d] + atomicAdd(&fill[d], 1);
    csr[pos] = make_float4(__int_as_float(ei[e]), ea[e * 3 + 0], ea[e * 3 + 1], ea[e * 3 + 2]);
}

// ---------------- h0 = x @ npW + npB ----------------
__global__ __launch_bounds__(256) void k_node_proj(const float* __restrict__ x, const float* __restrict__ W,
                                                   const float* __restrict__ b, float* __restrict__ h) {
    __shared__ float sW[28 * 128];
    __shared__ float sx[16 * 28];
    int t = threadIdx.x;
    for (int i = t; i < 28 * 128; i += 256) sW[i] = W[i];
    int row0 = blockIdx.x * 16;
    for (int i = t; i < 16 * 28; i += 256) {
        int r = row0 + i / 28;
        sx[i] = (r < NN) ? x[r * 28 + i % 28] : 0.f;
    }
    __syncthreads();
    int j = t & 127;
    int rsub = t >> 7;
    float bias = b[j];
    for (int i = 0; i < 8; ++i) {
        int r = rsub + 2 * i;
        int row = row0 + r;
        if (row >= NN) continue;
        float acc = bias;
        #pragma unroll
        for (int k = 0; k < 28; ++k) acc = fmaf(sx[r * 28 + k], sW[k * 128 + j], acc);
        h[row * 128 + j] = acc;
    }
}

// ---------------- fused [BN of prev layer] + xl/xr GEMM; TILE_M=16, W reg-prefetch ----------------
#define LOADW(dl, dr, kc) { _Pragma("unroll") for (int kk = 0; kk < 4; ++kk) { \
    dl[kk] = Wl4[((kc) * 4 + kk) * 32 + tx]; dr[kk] = Wr4[((kc) * 4 + kk) * 32 + tx]; } }

#define CHUNK(wl, wr, kc) { _Pragma("unroll") for (int kk = 0; kk < 4; ++kk) { \
    int k_ = (kc) * 4 + kk; \
    float a0 = sA[(r0 + 0) * 128 + k_]; \
    float a1 = sA[(r0 + 1) * 128 + k_]; \
    float vl0 = wl[kk].x, vl1 = wl[kk].y, vl2 = wl[kk].z, vl3 = wl[kk].w; \
    float vr0 = wr[kk].x, vr1 = wr[kk].y, vr2 = wr[kk].z, vr3 = wr[kk].w; \
    accL[0][0] = fmaf(a0, vl0, accL[0][0]); accL[0][1] = fmaf(a0, vl1, accL[0][1]); \
    accL[0][2] = fmaf(a0, vl2, accL[0][2]); accL[0][3] = fmaf(a0, vl3, accL[0][3]); \
    accL[1][0] = fmaf(a1, vl0, accL[1][0]); accL[1][1] = fmaf(a1, vl1, accL[1][1]); \
    accL[1][2] = fmaf(a1, vl2, accL[1][2]); accL[1][3] = fmaf(a1, vl3, accL[1][3]); \
    accR[0][0] = fmaf(a0, vr0, accR[0][0]); accR[0][1] = fmaf(a0, vr1, accR[0][1]); \
    accR[0][2] = fmaf(a0, vr2, accR[0][2]); accR[0][3] = fmaf(a0, vr3, accR[0][3]); \
    accR[1][0] = fmaf(a1, vr0, accR[1][0]); accR[1][1] = fmaf(a1, vr1, accR[1][1]); \
    accR[1][2] = fmaf(a1, vr2, accR[1][2]); accR[1][3] = fmaf(a1, vr3, accR[1][3]); } }

__global__ __launch_bounds__(256) void k_gemm(const float* __restrict__ hbuf,
                                              const float* __restrict__ gprev,
                                              const float* __restrict__ stats,
                                              const float* __restrict__ bngc, const float* __restrict__ bnbc,
                                              float* __restrict__ hout,
                                              const float* __restrict__ Wl, const float* __restrict__ bl,
                                              const float* __restrict__ Wr, const float* __restrict__ br,
                                              unsigned short* __restrict__ xlb, float* __restrict__ xr,
                                              int has_bn) {
    __shared__ float sA[16 * 128];   // 8 KB
    int t = threadIdx.x;
    int row0 = blockIdx.x * 16;
    const float invN = 1.f / (float)NN;
    for (int i = t; i < 16 * 32; i += 256) {
        int r = i >> 5, c4 = (i & 31) * 4;
        int row = row0 + r;
        float4 v = make_float4(0.f, 0.f, 0.f, 0.f);
        if (row < NN) {
            if (has_bn) {
                float4 gv = *(const float4*)&gprev[(size_t)row * 128 + c4];
                float4 hv = *(const float4*)&hbuf[(size_t)row * 128 + c4];
                float gg[4] = {gv.x, gv.y, gv.z, gv.w};
                float hh[4] = {hv.x, hv.y, hv.z, hv.w};
                float ov[4];
                #pragma unroll
                for (int j = 0; j < 4; ++j) {
                    int c = c4 + j;
                    float mean = stats[c] * invN;
                    float var  = stats[128 + c] * invN - mean * mean;
                    float sc   = bngc[c] * rsqrtf(var + BN_EPS);
                    float val  = fmaf(gg[j] - mean, sc, bnbc[c]);
                    val = val > 0.f ? val : 0.f;
                    ov[j] = val + hh[j];
                }
                v = make_float4(ov[0], ov[1], ov[2], ov[3]);
                *(float4*)&hout[(size_t)row * 128 + c4] = v;
            } else {
                v = *(const float4*)&hbuf[(size_t)row * 128 + c4];
            }
        }
        *(float4*)&sA[i * 4] = v;
    }
    __syncthreads();
    int tx = t & 31, ty = t >> 5;    // ty 0..7
    int j0 = tx * 4, r0 = ty * 2;
    const float4* Wl4 = (const float4*)Wl;
    const float4* Wr4 = (const float4*)Wr;
    float accL[2][4] = {{0}};
    float accR[2][4] = {{0}};
    float4 wlA[4], wrA[4], wlB[4], wrB[4];
    LOADW(wlA, wrA, 0);
    #pragma unroll 1
    for (int kc = 0; kc + 2 < 32; kc += 2) {
        LOADW(wlB, wrB, kc + 1);
        CHUNK(wlA, wrA, kc);
        LOADW(wlA, wrA, kc + 2);
        CHUNK(wlB, wrB, kc + 1);
    }
    LOADW(wlB, wrB, 31);
    CHUNK(wlA, wrA, 30);
    CHUNK(wlB, wrB, 31);
    float4 bl4 = *(const float4*)&bl[j0];
    float4 br4 = *(const float4*)&br[j0];
    #pragma unroll
    for (int i = 0; i < 2; ++i) {
        int row = row0 + r0 + i;
        if (row < NN) {
            float l0 = accL[i][0] + bl4.x, l1 = accL[i][1] + bl4.y;
            float l2 = accL[i][2] + bl4.z, l3 = accL[i][3] + bl4.w;
            uint2 pk;
            pk.x = f2bf(l0) | (f2bf(l1) << 16);
            pk.y = f2bf(l2) | (f2bf(l3) << 16);
            *(uint2*)&xlb[(size_t)row * 128 + j0] = pk;
            float4 oR = make_float4(accR[i][0] + br4.x, accR[i][1] + br4.y,
                                    accR[i][2] + br4.z, accR[i][3] + br4.w);
            *(float4*)&xr[(size_t)row * 128 + j0] = oR;
        }
    }
}

// ---------------- GAT: no-max softmax, 8 edges/iter main loop ----------------
__global__ __launch_bounds__(256) void k_gat(const unsigned short* __restrict__ xlb,
                                             const float* __restrict__ xr,
                                             const float4* __restrict__ csr, const int* __restrict__ rowstart,
                                             const int* __restrict__ cnt,
                                             const float* __restrict__ we3, // [4][128]
                                             const float* __restrict__ att, // [128]
                                             const float* __restrict__ gbias,
                                             float* __restrict__ g) {
    int wave = threadIdx.x >> 6;
    int lane = threadIdx.x & 63;
    int node = blockIdx.x * 4 + wave;
    if (node >= NN) return;
    int q = lane >> 4;      // edge slot 0..3
    int u = lane & 15;      // channel block
    int c0 = u * 8;
    float w0[8], w1[8], w2[8], wbx[8], at[8], xsl[8];
    LD8(w0, &we3[0 * 128 + c0]);
    LD8(w1, &we3[1 * 128 + c0]);
    LD8(w2, &we3[2 * 128 + c0]);
    LD8(wbx, &we3[3 * 128 + c0]);           // web
    {   // fold xr[node] into the bias base
        float tmp[8];
        LD8(tmp, &xr[(size_t)node * 128 + c0]);
        #pragma unroll
        for (int j = 0; j < 8; ++j) wbx[j] += tmp[j];
    }
    LD8(at, &att[c0]);
    LDBF8(xsl, &xlb[(size_t)node * 128 + c0]);
    int beg = rowstart[node];
    int deg = cnt[node];
    const unsigned short* xb = xlb + c0;
    float lr = 0.f;
    float o[8] = {0.f, 0.f, 0.f, 0.f, 0.f, 0.f, 0.f, 0.f};
    float sa0 = 0.f, sa1 = 0.f, sa2 = 0.f;
    int e0 = 0;
    for (; e0 + 8 <= deg; e0 += 8) {
        float4 ca = csr[beg + e0 + q];
        float4 cb = csr[beg + e0 + 4 + q];
        unsigned sa_ = (unsigned)__float_as_int(ca.x) << 7;
        unsigned sb_ = (unsigned)__float_as_int(cb.x) << 7;
        float xa[8], xbv[8];
        LDBF8(xa,  xb + sa_);
        LDBF8(xbv, xb + sb_);
        sa0 += ca.y + cb.y; sa1 += ca.z + cb.z; sa2 += ca.w + cb.w;
        float pa = 0.f, pb = 0.f;
        #pragma unroll
        for (int j = 0; j < 8; ++j) {
            float eepa = fmaf(ca.y, w0[j], fmaf(ca.z, w1[j], fmaf(ca.w, w2[j], wbx[j])));
            float va = xa[j] + eepa;
            float ma = fmaxf(va, LEAKY * va);
            pa = fmaf(ma, at[j], pa);
            float eepb = fmaf(cb.y, w0[j], fmaf(cb.z, w1[j], fmaf(cb.w, w2[j], wbx[j])));
            float vb = xbv[j] + eepb;
            float mb = fmaxf(vb, LEAKY * vb);
            pb = fmaf(mb, at[j], pb);
        }
        pa += __shfl_xor(pa, 1, 64); pa += __shfl_xor(pa, 2, 64);
        pb += __shfl_xor(pb, 1, 64); pb += __shfl_xor(pb, 2, 64);
        float ea_ = __expf(pa);
        float eb_ = __expf(pb);
        lr += ea_ + eb_;
        #pragma unroll
        for (int j = 0; j < 8; ++j) {
            o[j] = fmaf(ea_, xa[j], o[j]);
            o[j] = fmaf(eb_, xbv[j], o[j]);
        }
    }
    for (; e0 < deg; e0 += 4) {
        int e = e0 + q;
        bool valid = (e < deg);
        float4 c = csr[beg + (valid ? e : deg - 1)];
        unsigned s_ = (unsigned)__float_as_int(c.x) << 7;
        if (!valid) { c.y = 0.f; c.z = 0.f; c.w = 0.f; }
        float xls[8];
        LDBF8(xls, xb + s_);
        sa0 += c.y; sa1 += c.z; sa2 += c.w;
        float part = 0.f;
        #pragma unroll
        for (int j = 0; j < 8; ++j) {
            float eep = fmaf(c.y, w0[j], fmaf(c.z, w1[j], fmaf(c.w, w2[j], wbx[j])));
            float v = xls[j] + eep;
            float m = fmaxf(v, LEAKY * v);
            part = fmaf(m, at[j], part);
        }
        part += __shfl_xor(part, 1, 64); part += __shfl_xor(part, 2, 64);
        float p = valid ? __expf(part) : 0.f;
        lr += p;
        #pragma unroll
        for (int j = 0; j < 8; ++j) o[j] = fmaf(p, xls[j], o[j]);
    }
    sa0 += __shfl_xor(sa0, 16, 64); sa0 += __shfl_xor(sa0, 32, 64);
    sa1 += __shfl_xor(sa1, 16, 64); sa1 += __shfl_xor(sa1, 32, 64);
    sa2 += __shfl_xor(sa2, 16, 64); sa2 += __shfl_xor(sa2, 32, 64);
    { // self loop
        float part = 0.f;
        if (deg > 0) {
            float invd = 1.f / (float)deg;
            float ea0 = sa0 * invd, ea1 = sa1 * invd, ea2 = sa2 * invd;
            #pragma unroll
            for (int j = 0; j < 8; ++j) {
                float eep = fmaf(ea0, w0[j], fmaf(ea1, w1[j], fmaf(ea2, w2[j], wbx[j])));
                float v = xsl[j] + eep;
                float m = fmaxf(v, LEAKY * v);
                part = fmaf(m, at[j], part);
            }
        } else {
            float xrv[8];
            LD8(xrv, &xr[(size_t)node * 128 + c0]);
            #pragma unroll
            for (int j = 0; j < 8; ++j) {
                float v = xsl[j] + xrv[j];
                float m = fmaxf(v, LEAKY * v);
                part = fmaf(m, at[j], part);
            }
        }
        part += __shfl_xor(part, 1, 64); part += __shfl_xor(part, 2, 64);
        float p = (q == 0) ? __expf(part) : 0.f;
        lr += p;
        #pragma unroll
        for (int j = 0; j < 8; ++j) o[j] = fmaf(p, xsl[j], o[j]);
    }
    lr += __shfl_xor(lr, 16, 64); lr += __shfl_xor(lr, 32, 64);
    #pragma unroll
    for (int j = 0; j < 8; ++j) {
        o[j] += __shfl_xor(o[j], 16, 64);
        o[j] += __shfl_xor(o[j], 32, 64);
    }
    if (q == 0) {
        float inv = 1.f / (lr + 1e-16f);
        float gb[8];
        LD8(gb, &gbias[c0]);
        float4 r0 = make_float4(fmaf(o[0], inv, gb[0]), fmaf(o[1], inv, gb[1]),
                                fmaf(o[2], inv, gb[2]), fmaf(o[3], inv, gb[3]));
        float4 r1 = make_float4(fmaf(o[4], inv, gb[4]), fmaf(o[5], inv, gb[5]),
                                fmaf(o[6], inv, gb[6]), fmaf(o[7], inv, gb[7]));
        *(float4*)&g[(size_t)node * 128 + c0] = r0;
        *(float4*)&g[(size_t)node * 128 + c0 + 4] = r1;
    }
}

// ---------------- BN stats ----------------
__global__ __launch_bounds__(128) void k_bn_stats(const float* __restrict__ g, float* __restrict__ stats) {
    int c = threadIdx.x;
    float s = 0.f, sq = 0.f;
    for (int r = blockIdx.x; r < NN; r += gridDim.x) {
        float v = g[r * 128 + c];
        s += v;
        sq = fmaf(v, v, sq);
    }
    atomicAdd(&stats[c], s);
    atomicAdd(&stats[128 + c], sq);
}

// ---------------- MLP stage 1 ----------------
__global__ __launch_bounds__(256) void k_mlp1(const float* __restrict__ g, const float* __restrict__ h,
                                              const float* __restrict__ stats,
                                              const float* __restrict__ bngf, const float* __restrict__ bnbf,
                                              const int* __restrict__ mi, const float* __restrict__ pert,
                                              const float* __restrict__ r1W, const float* __restrict__ r1b,
                                              const float* __restrict__ bn1g, const float* __restrict__ bn1b,
                                              float* __restrict__ c1) {
    __shared__ float sm[64 * 137];
    __shared__ float sc1[64 * 16];
    __shared__ float sscale[16], sbeta[16];
    int t = threadIdx.x;
    const float invN = 1.f / (float)NN;
    for (int i = t; i < 64 * 137; i += 256) {
        int b = i / 137, k = i % 137;
        float val;
        if (k < 128) {
            int row = mi[b];
            float gv = g[(size_t)row * 128 + k];
            float hv = h[(size_t)row * 128 + k];
            float mean = stats[k] * invN;
            float var  = stats[128 + k] * invN - mean * mean;
            float sc   = bngf[k] * rsqrtf(var + BN_EPS);
            float v    = fmaf(gv - mean, sc, bnbf[k]);
            v = v > 0.f ? v : 0.f;
            val = v + hv;
        } else {
            val = pert[b * 9 + (k - 128)];
        }
        sm[i] = val;
    }
    __syncthreads();
    int jl = t & 15;
    int j  = blockIdx.x * 16 + jl;
    int b0 = (t >> 4) * 4;
    float acc[4];
    float bias = r1b[j];
    acc[0] = acc[1] = acc[2] = acc[3] = bias;
    for (int k = 0; k < 137; ++k) {
        float w = r1W[k * 256 + j];
        #pragma unroll
        for (int i = 0; i < 4; ++i) acc[i] = fmaf(sm[(b0 + i) * 137 + k], w, acc[i]);
    }
    #pragma unroll
    for (int i = 0; i < 4; ++i) sc1[(b0 + i) * 16 + jl] = acc[i];
    __syncthreads();
    if (t < 16) {
        float s = 0.f, sq = 0.f;
        for (int b = 0; b < 64; ++b) { float v = sc1[b * 16 + t]; s += v; sq = fmaf(v, v, sq); }
        float mean = s * (1.f / 64.f), var = sq * (1.f / 64.f) - mean * mean;
        int jj = blockIdx.x * 16 + t;
        float sc = bn1g[jj] * rsqrtf(var + BN_EPS);
        sscale[t] = sc;
        sbeta[t]  = bn1b[jj] - mean * sc;
    }
    __syncthreads();
    float sc = sscale[jl], be = sbeta[jl];
    #pragma unroll
    for (int i = 0; i < 4; ++i) {
        float v = fmaf(acc[i], sc, be);
        c1[(b0 + i) * 256 + j] = v > 0.f ? v : 0.f;
    }
}

// ---------------- MLP stage 2 ----------------
__global__ __launch_bounds__(256) void k_mlp2(const float* __restrict__ c1,
                                              const float* __restrict__ r2W, const float* __restrict__ r2b,
                                              const float* __restrict__ bn2g, const float* __restrict__ bn2b,
                                              float* __restrict__ c2) {
    __shared__ float sm[64 * 256];
    __shared__ float sc2[64 * 16];
    __shared__ float sscale[16], sbeta[16];
    int t = threadIdx.x;
    for (int i = t; i < 64 * 64; i += 256) *(float4*)&sm[i * 4] = *(const float4*)&c1[i * 4];
    __syncthreads();
    int jl = t & 15;
    int j  = blockIdx.x * 16 + jl;
    int b0 = (t >> 4) * 4;
    float acc[4];
    float bias = r2b[j];
    acc[0] = acc[1] = acc[2] = acc[3] = bias;
    for (int k = 0; k < 256; ++k) {
        float w = r2W[k * 128 + j];
        #pragma unroll
        for (int i = 0; i < 4; ++i) acc[i] = fmaf(sm[(b0 + i) * 256 + k], w, acc[i]);
    }
    #pragma unroll
    for (int i = 0; i < 4; ++i) sc2[(b0 + i) * 16 + jl] = acc[i];
    __syncthreads();
    if (t < 16) {
        float s = 0.f, sq = 0.f;
        for (int b = 0; b < 64; ++b) { float v = sc2[b * 16 + t]; s += v; sq = fmaf(v, v, sq); }
        float mean = s * (1.f / 64.f), var = sq * (1.f / 64.f) - mean * mean;
        int jj = blockIdx.x * 16 + t;
        float sc = bn2g[jj] * rsqrtf(var + BN_EPS);
        sscale[t] = sc;
        sbeta[t]  = bn2b[jj] - mean * sc;
    }
    __syncthreads();
    float sc = sscale[jl], be = sbeta[jl];
    #pragma unroll
    for (int i = 0; i < 4; ++i) {
        float v = fmaf(acc[i], sc, be);
        c2[(b0 + i) * 128 + j] = v > 0.f ? v : 0.f;
    }
}

// ---------------- MLP stage 3 ----------------
__global__ __launch_bounds__(256) void k_mlp3(const float* __restrict__ c2,
                                              const float* __restrict__ r3W, const float* __restrict__ r3b,
                                              const float* __restrict__ clsW, const float* __restrict__ clsb,
                                              const float* __restrict__ regW, const float* __restrict__ regb,
                                              float* __restrict__ out) {
    __shared__ float sm[64 * 128];
    __shared__ float sc3[64 * 64];
    int t = threadIdx.x;
    for (int i = t; i < 64 * 32; i += 256) *(float4*)&sm[i * 4] = *(const float4*)&c2[i * 4];
    __syncthreads();
    {
        int j = t & 63, bb = t >> 6;
        float acc[16];
        float bias = r3b[j];
        #pragma unroll
        for (int i = 0; i < 16; ++i) acc[i] = bias;
        for (int k = 0; k < 128; ++k) {
            float w = r3W[k * 64 + j];
            #pragma unroll
            for (int i = 0; i < 16; ++i) acc[i] = fmaf(sm[(bb + 4 * i) * 128 + k], w, acc[i]);
        }
        #pragma unroll
        for (int i = 0; i < 16; ++i) { float v = acc[i]; sc3[(bb + 4 * i) * 64 + j] = v > 0.f ? v : 0.f; }
    }
    __syncthreads();
    if (t < 128) {
        int b = t >> 1, which = t & 1;
        const float* W = which ? regW : clsW;
        float acc = which ? regb[0] : clsb[0];
        for (int k = 0; k < 64; ++k) acc = fmaf(sc3[b * 64 + k], W[k], acc);
        out[b * 2 + which] = acc;
    }
}

extern "C" void kernel_launch(void* const* d_in, const int* in_sizes, int n_in,
                              void* d_out, int out_size, void* d_ws, size_t ws_size,
                              hipStream_t stream) {
    const float* x    = (const float*)d_in[0];
    const float* ea   = (const float*)d_in[1];
    const int*   ei   = (const int*)d_in[2];
    const int*   mi   = (const int*)d_in[3];
    const float* pert = (const float*)d_in[4];
    const float* npW  = (const float*)d_in[5];
    const float* npB  = (const float*)d_in[6];
    const float* epW  = (const float*)d_in[7];
    const float* epB  = (const float*)d_in[8];
    const float* Wl   = (const float*)d_in[9];
    const float* bl   = (const float*)d_in[10];
    const float* Wr   = (const float*)d_in[11];
    const float* br   = (const float*)d_in[12];
    const float* We   = (const float*)d_in[13];
    const float* att  = (const float*)d_in[14];
    const float* gb   = (const float*)d_in[15];
    const float* bng  = (const float*)d_in[16];
    const float* bnb  = (const float*)d_in[17];
    const float* r1W  = (const float*)d_in[18];
    const float* r1b  = (const float*)d_in[19];
    const float* bn1g = (const float*)d_in[20];
    const float* bn1b = (const float*)d_in[21];
    const float* r2W  = (const float*)d_in[22];
    const float* r2b  = (const float*)d_in[23];
    const float* bn2g = (const float*)d_in[24];
    const float* bn2b = (const float*)d_in[25];
    const float* r3W  = (const float*)d_in[26];
    const float* r3b  = (const float*)d_in[27];
    const float* clsW = (const float*)d_in[28];
    const float* clsb = (const float*)d_in[29];
    const float* regW = (const float*)d_in[30];
    const float* regb = (const float*)d_in[31];
    float* out = (float*)d_out;

    float* ws = (float*)d_ws;
    int*   cnt      = (int*)(ws + OFF_CNT);
    int*   fill     = (int*)(ws + OFF_FILL);
    float* bnstats  = ws + OFF_BNSTATS;
    int*   rowstart = (int*)(ws + OFF_ROWSTART);
    float* we3web   = ws + OFF_WE3;
    float* h        = ws + OFF_H;
    unsigned short* xlb = (unsigned short*)(ws + OFF_XLB);
    float* xr       = ws + OFF_XR;
    float* g        = ws + OFF_G;
    float4* csr     = (float4*)(ws + OFF_CSR);
    float* c1       = ws + OFF_C1;
    float* c2       = ws + OFF_C2;

    hipMemsetAsync(ws, 0, ZERO_ELEMS * sizeof(float), stream);

    k_prep_we3<<<6, 256, 0, stream>>>(epW, epB, We, we3web);
    k_hist<<<(NE + 255) / 256, 256, 0, stream>>>(ei, cnt);
    k_scan<<<1, 1024, 0, stream>>>(cnt, rowstart);
    k_scatter<<<(NE + 255) / 256, 256, 0, stream>>>(ei, ea, rowstart, fill, csr);
    k_node_proj<<<(NN + 15) / 16, 256, 0, stream>>>(x, npW, npB, h);

    const int GEMM_BLOCKS = (NN + 15) / 16;
    for (int l = 0; l < NL; ++l) {
        if (l == 0) {
            k_gemm<<<GEMM_BLOCKS, 256, 0, stream>>>(h, nullptr, nullptr, nullptr, nullptr, h,
                                                    Wl + l * HID * HID, bl + l * HID,
                                                    Wr + l * HID * HID, br + l * HID, xlb, xr, 0);
        } else {
            k_gemm<<<GEMM_BLOCKS, 256, 0, stream>>>(h, g, bnstats + (l - 1) * 256,
                                                    bng + (l - 1) * 128, bnb + (l - 1) * 128, h,
                                                    Wl + l * HID * HID, bl + l * HID,
                                                    Wr + l * HID * HID, br + l * HID, xlb, xr, 1);
        }
        k_gat<<<(NN + 3) / 4, 256, 0, stream>>>(xlb, xr, csr, rowstart, cnt,
                                                we3web + l * 512, att + l * 128, gb + l * 128, g);
        k_bn_stats<<<512, 128, 0, stream>>>(g, bnstats + l * 256);
    }

    k_mlp1<<<16, 256, 0, stream>>>(g, h, bnstats + 2 * 256, bng + 2 * 128, bnb + 2 * 128,
                                   mi, pert, r1W, r1b, bn1g, bn1b, c1);
    k_mlp2<<<8, 256, 0, stream>>>(c1, r2W, r2b, bn2g, bn2b, c2);
    k_mlp3<<<1, 256, 0, stream>>>(c2, r3W, r3b, clsW, clsb, regW, regb, out);
    (void)in_sizes; (void)n_in; (void)out_size; (void)ws_size;
}

// Round 9
// 706.148 us; speedup vs baseline: 1.1075x; 1.1075x over previous
//
#include <hip/hip_runtime.h>
#include <hip/hip_bf16.h>

#define NN 30000
#define NE 960000
#define HID 128
#define NL 3
#define NB 64
#define BN_EPS 1e-5f
#define LEAKY 0.2f

// ---------------- workspace layout (float elements) ----------------
#define OFF_CNT      0
#define OFF_FILL     (OFF_CNT + NN)
#define OFF_BNSTATS  (OFF_FILL + NN)
#define ZERO_ELEMS   (OFF_BNSTATS + 3*256)
#define OFF_ROWSTART (ZERO_ELEMS)                    // NN+1 ints (pad 30016)
#define OFF_WE3      (OFF_ROWSTART + 30016)          // 3*4*128 floats
#define OFF_H        (OFF_WE3 + 1536)
#define OFF_XLB      (OFF_H  + NN*HID)               // bf16 [NN][128]
#define OFF_XR       (OFF_XLB + NN*HID/2)
#define OFF_G        (OFF_XR + NN*HID)
#define OFF_CSR      (OFF_G  + NN*HID)               // NE float4
#define OFF_C1       (OFF_CSR + NE*4)                // 64*256
#define OFF_C2       (OFF_C1 + 64*256)               // 64*128

#define LD8(dst, ptr) { float4 a_ = *(const float4*)(ptr); float4 b_ = *(const float4*)((ptr)+4); \
    dst[0]=a_.x; dst[1]=a_.y; dst[2]=a_.z; dst[3]=a_.w; dst[4]=b_.x; dst[5]=b_.y; dst[6]=b_.z; dst[7]=b_.w; }

// load 8 bf16 (16 B) and widen to fp32
#define LDBF8(dst, ptr) { uint4 t_ = *(const uint4*)(ptr); \
    dst[0]=__uint_as_float(t_.x<<16); dst[1]=__uint_as_float(t_.x&0xffff0000u); \
    dst[2]=__uint_as_float(t_.y<<16); dst[3]=__uint_as_float(t_.y&0xffff0000u); \
    dst[4]=__uint_as_float(t_.z<<16); dst[5]=__uint_as_float(t_.z&0xffff0000u); \
    dst[6]=__uint_as_float(t_.w<<16); dst[7]=__uint_as_float(t_.w&0xffff0000u); }

__device__ __forceinline__ unsigned f2bf(float f) { // round-to-nearest-even
    unsigned u = __float_as_uint(f);
    return (u + 0x7fffu + ((u >> 16) & 1u)) >> 16;
}

// ---------------- We3[l] = epW @ We[l], web[l] = epB @ We[l] ----------------
__global__ void k_prep_we3(const float* __restrict__ epW, const float* __restrict__ epB,
                           const float* __restrict__ We, float* __restrict__ we3web) {
    int idx = blockIdx.x * 256 + threadIdx.x;
    if (idx >= 3 * 512) return;
    int l = idx / 512, rem = idx % 512;
    int r = rem / 128, j = rem % 128;
    const float* W = We + l * HID * HID;
    float acc = 0.f;
    if (r < 3) {
        for (int c = 0; c < HID; ++c) acc = fmaf(epW[r * HID + c], W[c * HID + j], acc);
    } else {
        for (int c = 0; c < HID; ++c) acc = fmaf(epB[c], W[c * HID + j], acc);
    }
    we3web[l * 512 + r * 128 + j] = acc;
}

// ---------------- histogram ----------------
__global__ void k_hist(const int* __restrict__ ei, int* __restrict__ cnt) {
    int e = blockIdx.x * 256 + threadIdx.x;
    if (e >= NE) return;
    atomicAdd(&cnt[ei[NE + e]], 1);
}

// ---------------- exclusive scan ----------------
__global__ __launch_bounds__(1024) void k_scan(const int* __restrict__ cnt, int* __restrict__ rowstart) {
    __shared__ int s[1024];
    const int CH = 30;
    int t = threadIdx.x;
    int base = t * CH;
    int loc[CH];
    int sum = 0;
    #pragma unroll
    for (int i = 0; i < CH; ++i) {
        int idx = base + i;
        int v = (idx < NN) ? cnt[idx] : 0;
        loc[i] = sum;
        sum += v;
    }
    s[t] = sum;
    __syncthreads();
    for (int off = 1; off < 1024; off <<= 1) {
        int x = (t >= off) ? s[t - off] : 0;
        __syncthreads();
        s[t] += x;
        __syncthreads();
    }
    int carry = (t > 0) ? s[t - 1] : 0;
    #pragma unroll
    for (int i = 0; i < CH; ++i) {
        int idx = base + i;
        if (idx < NN) rowstart[idx] = carry + loc[i];
    }
    if (t == 1023) rowstart[NN] = s[1023];
}

// ---------------- scatter edges into CSR ----------------
__global__ void k_scatter(const int* __restrict__ ei, const float* __restrict__ ea,
                          const int* __restrict__ rowstart, int* __restrict__ fill,
                          float4* __restrict__ csr) {
    int e = blockIdx.x * 256 + threadIdx.x;
    if (e >= NE) return;
    int d = ei[NE + e];
    int pos = rowstart[d] + atomicAdd(&fill[d], 1);
    csr[pos] = make_float4(__int_as_float(ei[e]), ea[e * 3 + 0], ea[e * 3 + 1], ea[e * 3 + 2]);
}

// ---------------- h0 = x @ npW + npB ----------------
__global__ __launch_bounds__(256) void k_node_proj(const float* __restrict__ x, const float* __restrict__ W,
                                                   const float* __restrict__ b, float* __restrict__ h) {
    __shared__ float sW[28 * 128];
    __shared__ float sx[16 * 28];
    int t = threadIdx.x;
    for (int i = t; i < 28 * 128; i += 256) sW[i] = W[i];
    int row0 = blockIdx.x * 16;
    for (int i = t; i < 16 * 28; i += 256) {
        int r = row0 + i / 28;
        sx[i] = (r < NN) ? x[r * 28 + i % 28] : 0.f;
    }
    __syncthreads();
    int j = t & 127;
    int rsub = t >> 7;
    float bias = b[j];
    for (int i = 0; i < 8; ++i) {
        int r = rsub + 2 * i;
        int row = row0 + r;
        if (row >= NN) continue;
        float acc = bias;
        #pragma unroll
        for (int k = 0; k < 28; ++k) acc = fmaf(sx[r * 28 + k], sW[k * 128 + j], acc);
        h[row * 128 + j] = acc;
    }
}

// ---------------- fused [BN of prev layer] + xl/xr GEMM; TILE_M=32, W reg-prefetch (2k chunks) ----------------
#define LOADW(dl, dr, kc) { \
    dl[0] = Wl4[((kc) * 2 + 0) * 32 + tx]; dl[1] = Wl4[((kc) * 2 + 1) * 32 + tx]; \
    dr[0] = Wr4[((kc) * 2 + 0) * 32 + tx]; dr[1] = Wr4[((kc) * 2 + 1) * 32 + tx]; }

#define CHUNK(wl, wr, kc) { _Pragma("unroll") for (int kk = 0; kk < 2; ++kk) { \
    int k_ = (kc) * 2 + kk; \
    float a0 = sA[(r0 + 0) * 128 + k_]; \
    float a1 = sA[(r0 + 1) * 128 + k_]; \
    float a2 = sA[(r0 + 2) * 128 + k_]; \
    float a3 = sA[(r0 + 3) * 128 + k_]; \
    float vl0 = wl[kk].x, vl1 = wl[kk].y, vl2 = wl[kk].z, vl3 = wl[kk].w; \
    float vr0 = wr[kk].x, vr1 = wr[kk].y, vr2 = wr[kk].z, vr3 = wr[kk].w; \
    accL[0][0] = fmaf(a0, vl0, accL[0][0]); accL[0][1] = fmaf(a0, vl1, accL[0][1]); \
    accL[0][2] = fmaf(a0, vl2, accL[0][2]); accL[0][3] = fmaf(a0, vl3, accL[0][3]); \
    accL[1][0] = fmaf(a1, vl0, accL[1][0]); accL[1][1] = fmaf(a1, vl1, accL[1][1]); \
    accL[1][2] = fmaf(a1, vl2, accL[1][2]); accL[1][3] = fmaf(a1, vl3, accL[1][3]); \
    accL[2][0] = fmaf(a2, vl0, accL[2][0]); accL[2][1] = fmaf(a2, vl1, accL[2][1]); \
    accL[2][2] = fmaf(a2, vl2, accL[2][2]); accL[2][3] = fmaf(a2, vl3, accL[2][3]); \
    accL[3][0] = fmaf(a3, vl0, accL[3][0]); accL[3][1] = fmaf(a3, vl1, accL[3][1]); \
    accL[3][2] = fmaf(a3, vl2, accL[3][2]); accL[3][3] = fmaf(a3, vl3, accL[3][3]); \
    accR[0][0] = fmaf(a0, vr0, accR[0][0]); accR[0][1] = fmaf(a0, vr1, accR[0][1]); \
    accR[0][2] = fmaf(a0, vr2, accR[0][2]); accR[0][3] = fmaf(a0, vr3, accR[0][3]); \
    accR[1][0] = fmaf(a1, vr0, accR[1][0]); accR[1][1] = fmaf(a1, vr1, accR[1][1]); \
    accR[1][2] = fmaf(a1, vr2, accR[1][2]); accR[1][3] = fmaf(a1, vr3, accR[1][3]); \
    accR[2][0] = fmaf(a2, vr0, accR[2][0]); accR[2][1] = fmaf(a2, vr1, accR[2][1]); \
    accR[2][2] = fmaf(a2, vr2, accR[2][2]); accR[2][3] = fmaf(a2, vr3, accR[2][3]); \
    accR[3][0] = fmaf(a3, vr0, accR[3][0]); accR[3][1] = fmaf(a3, vr1, accR[3][1]); \
    accR[3][2] = fmaf(a3, vr2, accR[3][2]); accR[3][3] = fmaf(a3, vr3, accR[3][3]); } }

__global__ __launch_bounds__(256) void k_gemm(const float* __restrict__ hbuf,
                                              const float* __restrict__ gprev,
                                              const float* __restrict__ stats,
                                              const float* __restrict__ bngc, const float* __restrict__ bnbc,
                                              float* __restrict__ hout,
                                              const float* __restrict__ Wl, const float* __restrict__ bl,
                                              const float* __restrict__ Wr, const float* __restrict__ br,
                                              unsigned short* __restrict__ xlb, float* __restrict__ xr,
                                              int has_bn) {
    __shared__ float sA[32 * 128];   // 16 KB
    int t = threadIdx.x;
    int row0 = blockIdx.x * 32;
    const float invN = 1.f / (float)NN;
    for (int i = t; i < 32 * 32; i += 256) {
        int r = i >> 5, c4 = (i & 31) * 4;
        int row = row0 + r;
        float4 v = make_float4(0.f, 0.f, 0.f, 0.f);
        if (row < NN) {
            if (has_bn) {
                float4 gv = *(const float4*)&gprev[(size_t)row * 128 + c4];
                float4 hv = *(const float4*)&hbuf[(size_t)row * 128 + c4];
                float gg[4] = {gv.x, gv.y, gv.z, gv.w};
                float hh[4] = {hv.x, hv.y, hv.z, hv.w};
                float ov[4];
                #pragma unroll
                for (int j = 0; j < 4; ++j) {
                    int c = c4 + j;
                    float mean = stats[c] * invN;
                    float var  = stats[128 + c] * invN - mean * mean;
                    float sc   = bngc[c] * rsqrtf(var + BN_EPS);
                    float val  = fmaf(gg[j] - mean, sc, bnbc[c]);
                    val = val > 0.f ? val : 0.f;
                    ov[j] = val + hh[j];
                }
                v = make_float4(ov[0], ov[1], ov[2], ov[3]);
                *(float4*)&hout[(size_t)row * 128 + c4] = v;
            } else {
                v = *(const float4*)&hbuf[(size_t)row * 128 + c4];
            }
        }
        *(float4*)&sA[i * 4] = v;
    }
    __syncthreads();
    int tx = t & 31, ty = t >> 5;    // ty 0..7
    int j0 = tx * 4, r0 = ty * 4;
    const float4* Wl4 = (const float4*)Wl;
    const float4* Wr4 = (const float4*)Wr;
    float accL[4][4] = {{0}};
    float accR[4][4] = {{0}};
    float4 wlA[2], wrA[2], wlB[2], wrB[2];
    LOADW(wlA, wrA, 0);
    #pragma unroll 1
    for (int kc = 0; kc + 2 < 64; kc += 2) {
        LOADW(wlB, wrB, kc + 1);
        CHUNK(wlA, wrA, kc);
        LOADW(wlA, wrA, kc + 2);
        CHUNK(wlB, wrB, kc + 1);
    }
    LOADW(wlB, wrB, 63);
    CHUNK(wlA, wrA, 62);
    CHUNK(wlB, wrB, 63);
    float4 bl4 = *(const float4*)&bl[j0];
    float4 br4 = *(const float4*)&br[j0];
    #pragma unroll
    for (int i = 0; i < 4; ++i) {
        int row = row0 + r0 + i;
        if (row < NN) {
            float l0 = accL[i][0] + bl4.x, l1 = accL[i][1] + bl4.y;
            float l2 = accL[i][2] + bl4.z, l3 = accL[i][3] + bl4.w;
            uint2 pk;
            pk.x = f2bf(l0) | (f2bf(l1) << 16);
            pk.y = f2bf(l2) | (f2bf(l3) << 16);
            *(uint2*)&xlb[(size_t)row * 128 + j0] = pk;
            float4 oR = make_float4(accR[i][0] + br4.x, accR[i][1] + br4.y,
                                    accR[i][2] + br4.z, accR[i][3] + br4.w);
            *(float4*)&xr[(size_t)row * 128 + j0] = oR;
        }
    }
}

// ---------------- GAT: no-max softmax, 8 edges/iter main loop ----------------
__global__ __launch_bounds__(256) void k_gat(const unsigned short* __restrict__ xlb,
                                             const float* __restrict__ xr,
                                             const float4* __restrict__ csr, const int* __restrict__ rowstart,
                                             const int* __restrict__ cnt,
                                             const float* __restrict__ we3, // [4][128]
                                             const float* __restrict__ att, // [128]
                                             const float* __restrict__ gbias,
                                             float* __restrict__ g) {
    int wave = threadIdx.x >> 6;
    int lane = threadIdx.x & 63;
    int node = blockIdx.x * 4 + wave;
    if (node >= NN) return;
    int q = lane >> 4;      // edge slot 0..3
    int u = lane & 15;      // channel block
    int c0 = u * 8;
    float w0[8], w1[8], w2[8], wbx[8], at[8], xsl[8];
    LD8(w0, &we3[0 * 128 + c0]);
    LD8(w1, &we3[1 * 128 + c0]);
    LD8(w2, &we3[2 * 128 + c0]);
    LD8(wbx, &we3[3 * 128 + c0]);           // web
    {   // fold xr[node] into the bias base
        float tmp[8];
        LD8(tmp, &xr[(size_t)node * 128 + c0]);
        #pragma unroll
        for (int j = 0; j < 8; ++j) wbx[j] += tmp[j];
    }
    LD8(at, &att[c0]);
    LDBF8(xsl, &xlb[(size_t)node * 128 + c0]);
    int beg = rowstart[node];
    int deg = cnt[node];
    const unsigned short* xb = xlb + c0;
    float lr = 0.f;
    float o[8] = {0.f, 0.f, 0.f, 0.f, 0.f, 0.f, 0.f, 0.f};
    float sa0 = 0.f, sa1 = 0.f, sa2 = 0.f;
    int e0 = 0;
    for (; e0 + 8 <= deg; e0 += 8) {
        float4 ca = csr[beg + e0 + q];
        float4 cb = csr[beg + e0 + 4 + q];
        unsigned sa_ = (unsigned)__float_as_int(ca.x) << 7;
        unsigned sb_ = (unsigned)__float_as_int(cb.x) << 7;
        float xa[8], xbv[8];
        LDBF8(xa,  xb + sa_);
        LDBF8(xbv, xb + sb_);
        sa0 += ca.y + cb.y; sa1 += ca.z + cb.z; sa2 += ca.w + cb.w;
        float pa = 0.f, pb = 0.f;
        #pragma unroll
        for (int j = 0; j < 8; ++j) {
            float eepa = fmaf(ca.y, w0[j], fmaf(ca.z, w1[j], fmaf(ca.w, w2[j], wbx[j])));
            float va = xa[j] + eepa;
            float ma = fmaxf(va, LEAKY * va);
            pa = fmaf(ma, at[j], pa);
            float eepb = fmaf(cb.y, w0[j], fmaf(cb.z, w1[j], fmaf(cb.w, w2[j], wbx[j])));
            float vb = xbv[j] + eepb;
            float mb = fmaxf(vb, LEAKY * vb);
            pb = fmaf(mb, at[j], pb);
        }
        pa += __shfl_xor(pa, 1, 64); pa += __shfl_xor(pa, 2, 64);
        pb += __shfl_xor(pb, 1, 64); pb += __shfl_xor(pb, 2, 64);
        float ea_ = __expf(pa);
        float eb_ = __expf(pb);
        lr += ea_ + eb_;
        #pragma unroll
        for (int j = 0; j < 8; ++j) {
            o[j] = fmaf(ea_, xa[j], o[j]);
            o[j] = fmaf(eb_, xbv[j], o[j]);
        }
    }
    for (; e0 < deg; e0 += 4) {
        int e = e0 + q;
        bool valid = (e < deg);
        float4 c = csr[beg + (valid ? e : deg - 1)];
        unsigned s_ = (unsigned)__float_as_int(c.x) << 7;
        if (!valid) { c.y = 0.f; c.z = 0.f; c.w = 0.f; }
        float xls[8];
        LDBF8(xls, xb + s_);
        sa0 += c.y; sa1 += c.z; sa2 += c.w;
        float part = 0.f;
        #pragma unroll
        for (int j = 0; j < 8; ++j) {
            float eep = fmaf(c.y, w0[j], fmaf(c.z, w1[j], fmaf(c.w, w2[j], wbx[j])));
            float v = xls[j] + eep;
            float m = fmaxf(v, LEAKY * v);
            part = fmaf(m, at[j], part);
        }
        part += __shfl_xor(part, 1, 64); part += __shfl_xor(part, 2, 64);
        float p = valid ? __expf(part) : 0.f;
        lr += p;
        #pragma unroll
        for (int j = 0; j < 8; ++j) o[j] = fmaf(p, xls[j], o[j]);
    }
    sa0 += __shfl_xor(sa0, 16, 64); sa0 += __shfl_xor(sa0, 32, 64);
    sa1 += __shfl_xor(sa1, 16, 64); sa1 += __shfl_xor(sa1, 32, 64);
    sa2 += __shfl_xor(sa2, 16, 64); sa2 += __shfl_xor(sa2, 32, 64);
    { // self loop
        float part = 0.f;
        if (deg > 0) {
            float invd = 1.f / (float)deg;
            float ea0 = sa0 * invd, ea1 = sa1 * invd, ea2 = sa2 * invd;
            #pragma unroll
            for (int j = 0; j < 8; ++j) {
                float eep = fmaf(ea0, w0[j], fmaf(ea1, w1[j], fmaf(ea2, w2[j], wbx[j])));
                float v = xsl[j] + eep;
                float m = fmaxf(v, LEAKY * v);
                part = fmaf(m, at[j], part);
            }
        } else {
            float xrv[8];
            LD8(xrv, &xr[(size_t)node * 128 + c0]);
            #pragma unroll
            for (int j = 0; j < 8; ++j) {
                float v = xsl[j] + xrv[j];
                float m = fmaxf(v, LEAKY * v);
                part = fmaf(m, at[j], part);
            }
        }
        part += __shfl_xor(part, 1, 64); part += __shfl_xor(part, 2, 64);
        float p = (q == 0) ? __expf(part) : 0.f;
        lr += p;
        #pragma unroll
        for (int j = 0; j < 8; ++j) o[j] = fmaf(p, xsl[j], o[j]);
    }
    lr += __shfl_xor(lr, 16, 64); lr += __shfl_xor(lr, 32, 64);
    #pragma unroll
    for (int j = 0; j < 8; ++j) {
        o[j] += __shfl_xor(o[j], 16, 64);
        o[j] += __shfl_xor(o[j], 32, 64);
    }
    if (q == 0) {
        float inv = 1.f / (lr + 1e-16f);
        float gb[8];
        LD8(gb, &gbias[c0]);
        float4 r0 = make_float4(fmaf(o[0], inv, gb[0]), fmaf(o[1], inv, gb[1]),
                                fmaf(o[2], inv, gb[2]), fmaf(o[3], inv, gb[3]));
        float4 r1 = make_float4(fmaf(o[4], inv, gb[4]), fmaf(o[5], inv, gb[5]),
                                fmaf(o[6], inv, gb[6]), fmaf(o[7], inv, gb[7]));
        *(float4*)&g[(size_t)node * 128 + c0] = r0;
        *(float4*)&g[(size_t)node * 128 + c0 + 4] = r1;
    }
}

// ---------------- BN stats ----------------
__global__ __launch_bounds__(128) void k_bn_stats(const float* __restrict__ g, float* __restrict__ stats) {
    int c = threadIdx.x;
    float s = 0.f, sq = 0.f;
    for (int r = blockIdx.x; r < NN; r += gridDim.x) {
        float v = g[r * 128 + c];
        s += v;
        sq = fmaf(v, v, sq);
    }
    atomicAdd(&stats[c], s);
    atomicAdd(&stats[128 + c], sq);
}

// ---------------- MLP stage 1 ----------------
__global__ __launch_bounds__(256) void k_mlp1(const float* __restrict__ g, const float* __restrict__ h,
                                              const float* __restrict__ stats,
                                              const float* __restrict__ bngf, const float* __restrict__ bnbf,
                                              const int* __restrict__ mi, const float* __restrict__ pert,
                                              const float* __restrict__ r1W, const float* __restrict__ r1b,
                                              const float* __restrict__ bn1g, const float* __restrict__ bn1b,
                                              float* __restrict__ c1) {
    __shared__ float sm[64 * 137];
    __shared__ float sc1[64 * 16];
    __shared__ float sscale[16], sbeta[16];
    int t = threadIdx.x;
    const float invN = 1.f / (float)NN;
    for (int i = t; i < 64 * 137; i += 256) {
        int b = i / 137, k = i % 137;
        float val;
        if (k < 128) {
            int row = mi[b];
            float gv = g[(size_t)row * 128 + k];
            float hv = h[(size_t)row * 128 + k];
            float mean = stats[k] * invN;
            float var  = stats[128 + k] * invN - mean * mean;
            float sc   = bngf[k] * rsqrtf(var + BN_EPS);
            float v    = fmaf(gv - mean, sc, bnbf[k]);
            v = v > 0.f ? v : 0.f;
            val = v + hv;
        } else {
            val = pert[b * 9 + (k - 128)];
        }
        sm[i] = val;
    }
    __syncthreads();
    int jl = t & 15;
    int j  = blockIdx.x * 16 + jl;
    int b0 = (t >> 4) * 4;
    float acc[4];
    float bias = r1b[j];
    acc[0] = acc[1] = acc[2] = acc[3] = bias;
    for (int k = 0; k < 137; ++k) {
        float w = r1W[k * 256 + j];
        #pragma unroll
        for (int i = 0; i < 4; ++i) acc[i] = fmaf(sm[(b0 + i) * 137 + k], w, acc[i]);
    }
    #pragma unroll
    for (int i = 0; i < 4; ++i) sc1[(b0 + i) * 16 + jl] = acc[i];
    __syncthreads();
    if (t < 16) {
        float s = 0.f, sq = 0.f;
        for (int b = 0; b < 64; ++b) { float v = sc1[b * 16 + t]; s += v; sq = fmaf(v, v, sq); }
        float mean = s * (1.f / 64.f), var = sq * (1.f / 64.f) - mean * mean;
        int jj = blockIdx.x * 16 + t;
        float sc = bn1g[jj] * rsqrtf(var + BN_EPS);
        sscale[t] = sc;
        sbeta[t]  = bn1b[jj] - mean * sc;
    }
    __syncthreads();
    float sc = sscale[jl], be = sbeta[jl];
    #pragma unroll
    for (int i = 0; i < 4; ++i) {
        float v = fmaf(acc[i], sc, be);
        c1[(b0 + i) * 256 + j] = v > 0.f ? v : 0.f;
    }
}

// ---------------- MLP stage 2 ----------------
__global__ __launch_bounds__(256) void k_mlp2(const float* __restrict__ c1,
                                              const float* __restrict__ r2W, const float* __restrict__ r2b,
                                              const float* __restrict__ bn2g, const float* __restrict__ bn2b,
                                              float* __restrict__ c2) {
    __shared__ float sm[64 * 256];
    __shared__ float sc2[64 * 16];
    __shared__ float sscale[16], sbeta[16];
    int t = threadIdx.x;
    for (int i = t; i < 64 * 64; i += 256) *(float4*)&sm[i * 4] = *(const float4*)&c1[i * 4];
    __syncthreads();
    int jl = t & 15;
    int j  = blockIdx.x * 16 + jl;
    int b0 = (t >> 4) * 4;
    float acc[4];
    float bias = r2b[j];
    acc[0] = acc[1] = acc[2] = acc[3] = bias;
    for (int k = 0; k < 256; ++k) {
        float w = r2W[k * 128 + j];
        #pragma unroll
        for (int i = 0; i < 4; ++i) acc[i] = fmaf(sm[(b0 + i) * 256 + k], w, acc[i]);
    }
    #pragma unroll
    for (int i = 0; i < 4; ++i) sc2[(b0 + i) * 16 + jl] = acc[i];
    __syncthreads();
    if (t < 16) {
        float s = 0.f, sq = 0.f;
        for (int b = 0; b < 64; ++b) { float v = sc2[b * 16 + t]; s += v; sq = fmaf(v, v, sq); }
        float mean = s * (1.f / 64.f), var = sq * (1.f / 64.f) - mean * mean;
        int jj = blockIdx.x * 16 + t;
        float sc = bn2g[jj] * rsqrtf(var + BN_EPS);
        sscale[t] = sc;
        sbeta[t]  = bn2b[jj] - mean * sc;
    }
    __syncthreads();
    float sc = sscale[jl], be = sbeta[jl];
    #pragma unroll
    for (int i = 0; i < 4; ++i) {
        float v = fmaf(acc[i], sc, be);
        c2[(b0 + i) * 128 + j] = v > 0.f ? v : 0.f;
    }
}

// ---------------- MLP stage 3 ----------------
__global__ __launch_bounds__(256) void k_mlp3(const float* __restrict__ c2,
                                              const float* __restrict__ r3W, const float* __restrict__ r3b,
                                              const float* __restrict__ clsW, const float* __restrict__ clsb,
                                              const float* __restrict__ regW, const float* __restrict__ regb,
                                              float* __restrict__ out) {
    __shared__ float sm[64 * 128];
    __shared__ float sc3[64 * 64];
    int t = threadIdx.x;
    for (int i = t; i < 64 * 32; i += 256) *(float4*)&sm[i * 4] = *(const float4*)&c2[i * 4];
    __syncthreads();
    {
        int j = t & 63, bb = t >> 6;
        float acc[16];
        float bias = r3b[j];
        #pragma unroll
        for (int i = 0; i < 16; ++i) acc[i] = bias;
        for (int k = 0; k < 128; ++k) {
            float w = r3W[k * 64 + j];
            #pragma unroll
            for (int i = 0; i < 16; ++i) acc[i] = fmaf(sm[(bb + 4 * i) * 128 + k], w, acc[i]);
        }
        #pragma unroll
        for (int i = 0; i < 16; ++i) { float v = acc[i]; sc3[(bb + 4 * i) * 64 + j] = v > 0.f ? v : 0.f; }
    }
    __syncthreads();
    if (t < 128) {
        int b = t >> 1, which = t & 1;
        const float* W = which ? regW : clsW;
        float acc = which ? regb[0] : clsb[0];
        for (int k = 0; k < 64; ++k) acc = fmaf(sc3[b * 64 + k], W[k], acc);
        out[b * 2 + which] = acc;
    }
}

extern "C" void kernel_launch(void* const* d_in, const int* in_sizes, int n_in,
                              void* d_out, int out_size, void* d_ws, size_t ws_size,
                              hipStream_t stream) {
    const float* x    = (const float*)d_in[0];
    const float* ea   = (const float*)d_in[1];
    const int*   ei   = (const int*)d_in[2];
    const int*   mi   = (const int*)d_in[3];
    const float* pert = (const float*)d_in[4];
    const float* npW  = (const float*)d_in[5];
    const float* npB  = (const float*)d_in[6];
    const float* epW  = (const float*)d_in[7];
    const float* epB  = (const float*)d_in[8];
    const float* Wl   = (const float*)d_in[9];
    const float* bl   = (const float*)d_in[10];
    const float* Wr   = (const float*)d_in[11];
    const float* br   = (const float*)d_in[12];
    const float* We   = (const float*)d_in[13];
    const float* att  = (const float*)d_in[14];
    const float* gb   = (const float*)d_in[15];
    const float* bng  = (const float*)d_in[16];
    const float* bnb  = (const float*)d_in[17];
    const float* r1W  = (const float*)d_in[18];
    const float* r1b  = (const float*)d_in[19];
    const float* bn1g = (const float*)d_in[20];
    const float* bn1b = (const float*)d_in[21];
    const float* r2W  = (const float*)d_in[22];
    const float* r2b  = (const float*)d_in[23];
    const float* bn2g = (const float*)d_in[24];
    const float* bn2b = (const float*)d_in[25];
    const float* r3W  = (const float*)d_in[26];
    const float* r3b  = (const float*)d_in[27];
    const float* clsW = (const float*)d_in[28];
    const float* clsb = (const float*)d_in[29];
    const float* regW = (const float*)d_in[30];
    const float* regb = (const float*)d_in[31];
    float* out = (float*)d_out;

    float* ws = (float*)d_ws;
    int*   cnt      = (int*)(ws + OFF_CNT);
    int*   fill     = (int*)(ws + OFF_FILL);
    float* bnstats  = ws + OFF_BNSTATS;
    int*   rowstart = (int*)(ws + OFF_ROWSTART);
    float* we3web   = ws + OFF_WE3;
    float* h        = ws + OFF_H;
    unsigned short* xlb = (unsigned short*)(ws + OFF_XLB);
    float* xr       = ws + OFF_XR;
    float* g        = ws + OFF_G;
    float4* csr     = (float4*)(ws + OFF_CSR);
    float* c1       = ws + OFF_C1;
    float* c2       = ws + OFF_C2;

    hipMemsetAsync(ws, 0, ZERO_ELEMS * sizeof(float), stream);

    k_prep_we3<<<6, 256, 0, stream>>>(epW, epB, We, we3web);
    k_hist<<<(NE + 255) / 256, 256, 0, stream>>>(ei, cnt);
    k_scan<<<1, 1024, 0, stream>>>(cnt, rowstart);
    k_scatter<<<(NE + 255) / 256, 256, 0, stream>>>(ei, ea, rowstart, fill, csr);
    k_node_proj<<<(NN + 15) / 16, 256, 0, stream>>>(x, npW, npB, h);

    const int GEMM_BLOCKS = (NN + 31) / 32;
    for (int l = 0; l < NL; ++l) {
        if (l == 0) {
            k_gemm<<<GEMM_BLOCKS, 256, 0, stream>>>(h, nullptr, nullptr, nullptr, nullptr, h,
                                                    Wl + l * HID * HID, bl + l * HID,
                                                    Wr + l * HID * HID, br + l * HID, xlb, xr, 0);
        } else {
            k_gemm<<<GEMM_BLOCKS, 256, 0, stream>>>(h, g, bnstats + (l - 1) * 256,
                                                    bng + (l - 1) * 128, bnb + (l - 1) * 128, h,
                                                    Wl + l * HID * HID, bl + l * HID,
                                                    Wr + l * HID * HID, br + l * HID, xlb, xr, 1);
        }
        k_gat<<<(NN + 3) / 4, 256, 0, stream>>>(xlb, xr, csr, rowstart, cnt,
                                                we3web + l * 512, att + l * 128, gb + l * 128, g);
        k_bn_stats<<<512, 128, 0, stream>>>(g, bnstats + l * 256);
    }

    k_mlp1<<<16, 256, 0, stream>>>(g, h, bnstats + 2 * 256, bng + 2 * 128, bnb + 2 * 128,
                                   mi, pert, r1W, r1b, bn1g, bn1b, c1);
    k_mlp2<<<8, 256, 0, stream>>>(c1, r2W, r2b, bn2g, bn2b, c2);
    k_mlp3<<<1, 256, 0, stream>>>(c2, r3W, r3b, clsW, clsb, regW, regb, out);
    (void)in_sizes; (void)n_in; (void)out_size; (void)ws_size;
}

// Round 10
// 682.868 us; speedup vs baseline: 1.1453x; 1.0341x over previous
//
#include <hip/hip_runtime.h>
#include <hip/hip_bf16.h>

#define NN 30000
#define NE 960000
#define HID 128
#define NL 3
#define NB 64
#define BN_EPS 1e-5f
#define LEAKY 0.2f

// ---------------- workspace layout (float elements) ----------------
#define OFF_CNT      0
#define OFF_FILL     (OFF_CNT + NN)
#define OFF_BNSTATS  (OFF_FILL + NN)
#define ZERO_ELEMS   (OFF_BNSTATS + 3*256)
#define OFF_ROWSTART (ZERO_ELEMS)                    // NN+1 ints (pad 30016)
#define OFF_WE3      (OFF_ROWSTART + 30016)          // 3*4*128 floats
#define OFF_H        (OFF_WE3 + 1536)
#define OFF_XLB      (OFF_H  + NN*HID)               // bf16 [NN][128]
#define OFF_XR       (OFF_XLB + NN*HID/2)
#define OFF_G        (OFF_XR + NN*HID)
#define OFF_CSR      (OFF_G  + NN*HID)               // NE float4
#define OFF_C1       (OFF_CSR + NE*4)                // 64*256
#define OFF_C2       (OFF_C1 + 64*256)               // 64*128

#define LD8(dst, ptr) { float4 a_ = *(const float4*)(ptr); float4 b_ = *(const float4*)((ptr)+4); \
    dst[0]=a_.x; dst[1]=a_.y; dst[2]=a_.z; dst[3]=a_.w; dst[4]=b_.x; dst[5]=b_.y; dst[6]=b_.z; dst[7]=b_.w; }

// load 8 bf16 (16 B) and widen to fp32
#define LDBF8(dst, ptr) { uint4 t_ = *(const uint4*)(ptr); \
    dst[0]=__uint_as_float(t_.x<<16); dst[1]=__uint_as_float(t_.x&0xffff0000u); \
    dst[2]=__uint_as_float(t_.y<<16); dst[3]=__uint_as_float(t_.y&0xffff0000u); \
    dst[4]=__uint_as_float(t_.z<<16); dst[5]=__uint_as_float(t_.z&0xffff0000u); \
    dst[6]=__uint_as_float(t_.w<<16); dst[7]=__uint_as_float(t_.w&0xffff0000u); }

__device__ __forceinline__ unsigned f2bf(float f) { // round-to-nearest-even
    unsigned u = __float_as_uint(f);
    return (u + 0x7fffu + ((u >> 16) & 1u)) >> 16;
}

// ---------------- We3[l] = epW @ We[l], web[l] = epB @ We[l] ----------------
__global__ void k_prep_we3(const float* __restrict__ epW, const float* __restrict__ epB,
                           const float* __restrict__ We, float* __restrict__ we3web) {
    int idx = blockIdx.x * 256 + threadIdx.x;
    if (idx >= 3 * 512) return;
    int l = idx / 512, rem = idx % 512;
    int r = rem / 128, j = rem % 128;
    const float* W = We + l * HID * HID;
    float acc = 0.f;
    if (r < 3) {
        for (int c = 0; c < HID; ++c) acc = fmaf(epW[r * HID + c], W[c * HID + j], acc);
    } else {
        for (int c = 0; c < HID; ++c) acc = fmaf(epB[c], W[c * HID + j], acc);
    }
    we3web[l * 512 + r * 128 + j] = acc;
}

// ---------------- histogram ----------------
__global__ void k_hist(const int* __restrict__ ei, int* __restrict__ cnt) {
    int e = blockIdx.x * 256 + threadIdx.x;
    if (e >= NE) return;
    atomicAdd(&cnt[ei[NE + e]], 1);
}

// ---------------- exclusive scan ----------------
__global__ __launch_bounds__(1024) void k_scan(const int* __restrict__ cnt, int* __restrict__ rowstart) {
    __shared__ int s[1024];
    const int CH = 30;
    int t = threadIdx.x;
    int base = t * CH;
    int loc[CH];
    int sum = 0;
    #pragma unroll
    for (int i = 0; i < CH; ++i) {
        int idx = base + i;
        int v = (idx < NN) ? cnt[idx] : 0;
        loc[i] = sum;
        sum += v;
    }
    s[t] = sum;
    __syncthreads();
    for (int off = 1; off < 1024; off <<= 1) {
        int x = (t >= off) ? s[t - off] : 0;
        __syncthreads();
        s[t] += x;
        __syncthreads();
    }
    int carry = (t > 0) ? s[t - 1] : 0;
    #pragma unroll
    for (int i = 0; i < CH; ++i) {
        int idx = base + i;
        if (idx < NN) rowstart[idx] = carry + loc[i];
    }
    if (t == 1023) rowstart[NN] = s[1023];
}

// ---------------- scatter edges into CSR ----------------
__global__ void k_scatter(const int* __restrict__ ei, const float* __restrict__ ea,
                          const int* __restrict__ rowstart, int* __restrict__ fill,
                          float4* __restrict__ csr) {
    int e = blockIdx.x * 256 + threadIdx.x;
    if (e >= NE) return;
    int d = ei[NE + e];
    int pos = rowstart[d] + atomicAdd(&fill[d], 1);
    csr[pos] = make_float4(__int_as_float(ei[e]), ea[e * 3 + 0], ea[e * 3 + 1], ea[e * 3 + 2]);
}

// ---------------- h0 = x @ npW + npB ----------------
__global__ __launch_bounds__(256) void k_node_proj(const float* __restrict__ x, const float* __restrict__ W,
                                                   const float* __restrict__ b, float* __restrict__ h) {
    __shared__ float sW[28 * 128];
    __shared__ float sx[16 * 28];
    int t = threadIdx.x;
    for (int i = t; i < 28 * 128; i += 256) sW[i] = W[i];
    int row0 = blockIdx.x * 16;
    for (int i = t; i < 16 * 28; i += 256) {
        int r = row0 + i / 28;
        sx[i] = (r < NN) ? x[r * 28 + i % 28] : 0.f;
    }
    __syncthreads();
    int j = t & 127;
    int rsub = t >> 7;
    float bias = b[j];
    for (int i = 0; i < 8; ++i) {
        int r = rsub + 2 * i;
        int row = row0 + r;
        if (row >= NN) continue;
        float acc = bias;
        #pragma unroll
        for (int k = 0; k < 28; ++k) acc = fmaf(sx[r * 28 + k], sW[k * 128 + j], acc);
        h[row * 128 + j] = acc;
    }
}

// ---------------- fused [BN of prev layer] + xl/xr GEMM; TILE_M=64, W reg-prefetch ----------------
#define LOADW(dl, dr, kc) { \
    dl[0] = Wl4[((kc) * 2 + 0) * 32 + tx]; dl[1] = Wl4[((kc) * 2 + 1) * 32 + tx]; \
    dr[0] = Wr4[((kc) * 2 + 0) * 32 + tx]; dr[1] = Wr4[((kc) * 2 + 1) * 32 + tx]; }

#define CHUNK(wl, wr, kc) { _Pragma("unroll") for (int kk = 0; kk < 2; ++kk) { \
    int k_ = (kc) * 2 + kk; \
    float a[8]; \
    _Pragma("unroll") for (int i = 0; i < 8; ++i) a[i] = sA[(r0 + i) * 128 + k_]; \
    float vl0 = wl[kk].x, vl1 = wl[kk].y, vl2 = wl[kk].z, vl3 = wl[kk].w; \
    float vr0 = wr[kk].x, vr1 = wr[kk].y, vr2 = wr[kk].z, vr3 = wr[kk].w; \
    _Pragma("unroll") for (int i = 0; i < 8; ++i) { \
        accL[i][0] = fmaf(a[i], vl0, accL[i][0]); accL[i][1] = fmaf(a[i], vl1, accL[i][1]); \
        accL[i][2] = fmaf(a[i], vl2, accL[i][2]); accL[i][3] = fmaf(a[i], vl3, accL[i][3]); \
        accR[i][0] = fmaf(a[i], vr0, accR[i][0]); accR[i][1] = fmaf(a[i], vr1, accR[i][1]); \
        accR[i][2] = fmaf(a[i], vr2, accR[i][2]); accR[i][3] = fmaf(a[i], vr3, accR[i][3]); } } }

__global__ __launch_bounds__(256) void k_gemm(const float* __restrict__ hbuf,
                                              const float* __restrict__ gprev,
                                              const float* __restrict__ stats,
                                              const float* __restrict__ bngc, const float* __restrict__ bnbc,
                                              float* __restrict__ hout,
                                              const float* __restrict__ Wl, const float* __restrict__ bl,
                                              const float* __restrict__ Wr, const float* __restrict__ br,
                                              unsigned short* __restrict__ xlb, float* __restrict__ xr,
                                              int has_bn) {
    __shared__ float sA[64 * 128];   // 32 KB
    int t = threadIdx.x;
    int row0 = blockIdx.x * 64;
    const float invN = 1.f / (float)NN;
    for (int i = t; i < 64 * 32; i += 256) {
        int r = i >> 5, c4 = (i & 31) * 4;
        int row = row0 + r;
        float4 v = make_float4(0.f, 0.f, 0.f, 0.f);
        if (row < NN) {
            if (has_bn) {
                float4 gv = *(const float4*)&gprev[(size_t)row * 128 + c4];
                float4 hv = *(const float4*)&hbuf[(size_t)row * 128 + c4];
                float gg[4] = {gv.x, gv.y, gv.z, gv.w};
                float hh[4] = {hv.x, hv.y, hv.z, hv.w};
                float ov[4];
                #pragma unroll
                for (int j = 0; j < 4; ++j) {
                    int c = c4 + j;
                    float mean = stats[c] * invN;
                    float var  = stats[128 + c] * invN - mean * mean;
                    float sc   = bngc[c] * rsqrtf(var + BN_EPS);
                    float val  = fmaf(gg[j] - mean, sc, bnbc[c]);
                    val = val > 0.f ? val : 0.f;
                    ov[j] = val + hh[j];
                }
                v = make_float4(ov[0], ov[1], ov[2], ov[3]);
                *(float4*)&hout[(size_t)row * 128 + c4] = v;
            } else {
                v = *(const float4*)&hbuf[(size_t)row * 128 + c4];
            }
        }
        *(float4*)&sA[i * 4] = v;
    }
    __syncthreads();
    int tx = t & 31, ty = t >> 5;    // ty 0..7
    int j0 = tx * 4, r0 = ty * 8;
    const float4* Wl4 = (const float4*)Wl;
    const float4* Wr4 = (const float4*)Wr;
    float accL[8][4] = {{0}};
    float accR[8][4] = {{0}};
    float4 wlA[2], wrA[2], wlB[2], wrB[2];
    LOADW(wlA, wrA, 0);
    #pragma unroll 1
    for (int kc = 0; kc + 2 < 64; kc += 2) {
        LOADW(wlB, wrB, kc + 1);
        CHUNK(wlA, wrA, kc);
        LOADW(wlA, wrA, kc + 2);
        CHUNK(wlB, wrB, kc + 1);
    }
    LOADW(wlB, wrB, 63);
    CHUNK(wlA, wrA, 62);
    CHUNK(wlB, wrB, 63);
    float4 bl4 = *(const float4*)&bl[j0];
    float4 br4 = *(const float4*)&br[j0];
    #pragma unroll
    for (int i = 0; i < 8; ++i) {
        int row = row0 + r0 + i;
        if (row < NN) {
            float l0 = accL[i][0] + bl4.x, l1 = accL[i][1] + bl4.y;
            float l2 = accL[i][2] + bl4.z, l3 = accL[i][3] + bl4.w;
            uint2 pk;
            pk.x = f2bf(l0) | (f2bf(l1) << 16);
            pk.y = f2bf(l2) | (f2bf(l3) << 16);
            *(uint2*)&xlb[(size_t)row * 128 + j0] = pk;
            float4 oR = make_float4(accR[i][0] + br4.x, accR[i][1] + br4.y,
                                    accR[i][2] + br4.z, accR[i][3] + br4.w);
            *(float4*)&xr[(size_t)row * 128 + j0] = oR;
        }
    }
}

// ---------------- GAT: no-max softmax; leaky folded as 0.6v+0.4|v| into att weights ----------------
__global__ __launch_bounds__(256) void k_gat(const unsigned short* __restrict__ xlb,
                                             const float* __restrict__ xr,
                                             const float4* __restrict__ csr, const int* __restrict__ rowstart,
                                             const int* __restrict__ cnt,
                                             const float* __restrict__ we3, // [4][128]
                                             const float* __restrict__ att, // [128]
                                             const float* __restrict__ gbias,
                                             float* __restrict__ g) {
    int wave = threadIdx.x >> 6;
    int lane = threadIdx.x & 63;
    int node = blockIdx.x * 4 + wave;
    if (node >= NN) return;
    int q = lane >> 4;      // edge slot 0..3
    int u = lane & 15;      // channel block
    int c0 = u * 8;
    float w0[8], w1[8], w2[8], wbx[8], at6[8], at4[8], xsl[8];
    LD8(w0, &we3[0 * 128 + c0]);
    LD8(w1, &we3[1 * 128 + c0]);
    LD8(w2, &we3[2 * 128 + c0]);
    LD8(wbx, &we3[3 * 128 + c0]);           // web
    {   // fold xr[node] into the bias base
        float tmp[8];
        LD8(tmp, &xr[(size_t)node * 128 + c0]);
        #pragma unroll
        for (int j = 0; j < 8; ++j) wbx[j] += tmp[j];
    }
    {   // att split: att*leaky(v) == (0.6*att)*v + (0.4*att)*|v|  (slope 0.2)
        float tmp[8];
        LD8(tmp, &att[c0]);
        #pragma unroll
        for (int j = 0; j < 8; ++j) { at6[j] = 0.6f * tmp[j]; at4[j] = 0.4f * tmp[j]; }
    }
    LDBF8(xsl, &xlb[(size_t)node * 128 + c0]);
    int beg = rowstart[node];
    int deg = cnt[node];
    const unsigned short* xb = xlb + c0;
    float lr = 0.f;
    float o[8] = {0.f, 0.f, 0.f, 0.f, 0.f, 0.f, 0.f, 0.f};
    float sa0 = 0.f, sa1 = 0.f, sa2 = 0.f;
    int e0 = 0;
    for (; e0 + 8 <= deg; e0 += 8) {
        float4 ca = csr[beg + e0 + q];
        float4 cb = csr[beg + e0 + 4 + q];
        unsigned sa_ = (unsigned)__float_as_int(ca.x) << 7;
        unsigned sb_ = (unsigned)__float_as_int(cb.x) << 7;
        float xa[8], xbv[8];
        LDBF8(xa,  xb + sa_);
        LDBF8(xbv, xb + sb_);
        sa0 += ca.y + cb.y; sa1 += ca.z + cb.z; sa2 += ca.w + cb.w;
        float pa = 0.f, pb = 0.f;
        #pragma unroll
        for (int j = 0; j < 8; ++j) {
            float va = xa[j] + fmaf(ca.y, w0[j], fmaf(ca.z, w1[j], fmaf(ca.w, w2[j], wbx[j])));
            pa = fmaf(at6[j], va, fmaf(at4[j], fabsf(va), pa));
            float vb = xbv[j] + fmaf(cb.y, w0[j], fmaf(cb.z, w1[j], fmaf(cb.w, w2[j], wbx[j])));
            pb = fmaf(at6[j], vb, fmaf(at4[j], fabsf(vb), pb));
        }
        pa += __shfl_xor(pa, 1, 64); pa += __shfl_xor(pa, 2, 64);
        pb += __shfl_xor(pb, 1, 64); pb += __shfl_xor(pb, 2, 64);
        float ea_ = __expf(pa);
        float eb_ = __expf(pb);
        lr += ea_ + eb_;
        #pragma unroll
        for (int j = 0; j < 8; ++j) {
            o[j] = fmaf(ea_, xa[j], o[j]);
            o[j] = fmaf(eb_, xbv[j], o[j]);
        }
    }
    for (; e0 < deg; e0 += 4) {
        int e = e0 + q;
        bool valid = (e < deg);
        float4 c = csr[beg + (valid ? e : deg - 1)];
        unsigned s_ = (unsigned)__float_as_int(c.x) << 7;
        if (!valid) { c.y = 0.f; c.z = 0.f; c.w = 0.f; }
        float xls[8];
        LDBF8(xls, xb + s_);
        sa0 += c.y; sa1 += c.z; sa2 += c.w;
        float part = 0.f;
        #pragma unroll
        for (int j = 0; j < 8; ++j) {
            float v = xls[j] + fmaf(c.y, w0[j], fmaf(c.z, w1[j], fmaf(c.w, w2[j], wbx[j])));
            part = fmaf(at6[j], v, fmaf(at4[j], fabsf(v), part));
        }
        part += __shfl_xor(part, 1, 64); part += __shfl_xor(part, 2, 64);
        float p = valid ? __expf(part) : 0.f;
        lr += p;
        #pragma unroll
        for (int j = 0; j < 8; ++j) o[j] = fmaf(p, xls[j], o[j]);
    }
    sa0 += __shfl_xor(sa0, 16, 64); sa0 += __shfl_xor(sa0, 32, 64);
    sa1 += __shfl_xor(sa1, 16, 64); sa1 += __shfl_xor(sa1, 32, 64);
    sa2 += __shfl_xor(sa2, 16, 64); sa2 += __shfl_xor(sa2, 32, 64);
    { // self loop
        float part = 0.f;
        if (deg > 0) {
            float invd = 1.f / (float)deg;
            float ea0 = sa0 * invd, ea1 = sa1 * invd, ea2 = sa2 * invd;
            #pragma unroll
            for (int j = 0; j < 8; ++j) {
                float v = xsl[j] + fmaf(ea0, w0[j], fmaf(ea1, w1[j], fmaf(ea2, w2[j], wbx[j])));
                part = fmaf(at6[j], v, fmaf(at4[j], fabsf(v), part));
            }
        } else {
            float xrv[8];
            LD8(xrv, &xr[(size_t)node * 128 + c0]);
            #pragma unroll
            for (int j = 0; j < 8; ++j) {
                float v = xsl[j] + xrv[j];
                part = fmaf(at6[j], v, fmaf(at4[j], fabsf(v), part));
            }
        }
        part += __shfl_xor(part, 1, 64); part += __shfl_xor(part, 2, 64);
        float p = (q == 0) ? __expf(part) : 0.f;
        lr += p;
        #pragma unroll
        for (int j = 0; j < 8; ++j) o[j] = fmaf(p, xsl[j], o[j]);
    }
    lr += __shfl_xor(lr, 16, 64); lr += __shfl_xor(lr, 32, 64);
    #pragma unroll
    for (int j = 0; j < 8; ++j) {
        o[j] += __shfl_xor(o[j], 16, 64);
        o[j] += __shfl_xor(o[j], 32, 64);
    }
    if (q == 0) {
        float inv = 1.f / (lr + 1e-16f);
        float gb[8];
        LD8(gb, &gbias[c0]);
        float4 r0 = make_float4(fmaf(o[0], inv, gb[0]), fmaf(o[1], inv, gb[1]),
                                fmaf(o[2], inv, gb[2]), fmaf(o[3], inv, gb[3]));
        float4 r1 = make_float4(fmaf(o[4], inv, gb[4]), fmaf(o[5], inv, gb[5]),
                                fmaf(o[6], inv, gb[6]), fmaf(o[7], inv, gb[7]));
        *(float4*)&g[(size_t)node * 128 + c0] = r0;
        *(float4*)&g[(size_t)node * 128 + c0 + 4] = r1;
    }
}

// ---------------- BN stats ----------------
__global__ __launch_bounds__(128) void k_bn_stats(const float* __restrict__ g, float* __restrict__ stats) {
    int c = threadIdx.x;
    float s = 0.f, sq = 0.f;
    for (int r = blockIdx.x; r < NN; r += gridDim.x) {
        float v = g[r * 128 + c];
        s += v;
        sq = fmaf(v, v, sq);
    }
    atomicAdd(&stats[c], s);
    atomicAdd(&stats[128 + c], sq);
}

// ---------------- MLP stage 1 ----------------
__global__ __launch_bounds__(256) void k_mlp1(const float* __restrict__ g, const float* __restrict__ h,
                                              const float* __restrict__ stats,
                                              const float* __restrict__ bngf, const float* __restrict__ bnbf,
                                              const int* __restrict__ mi, const float* __restrict__ pert,
                                              const float* __restrict__ r1W, const float* __restrict__ r1b,
                                              const float* __restrict__ bn1g, const float* __restrict__ bn1b,
                                              float* __restrict__ c1) {
    __shared__ float sm[64 * 137];
    __shared__ float sc1[64 * 16];
    __shared__ float sscale[16], sbeta[16];
    int t = threadIdx.x;
    const float invN = 1.f / (float)NN;
    for (int i = t; i < 64 * 137; i += 256) {
        int b = i / 137, k = i % 137;
        float val;
        if (k < 128) {
            int row = mi[b];
            float gv = g[(size_t)row * 128 + k];
            float hv = h[(size_t)row * 128 + k];
            float mean = stats[k] * invN;
            float var  = stats[128 + k] * invN - mean * mean;
            float sc   = bngf[k] * rsqrtf(var + BN_EPS);
            float v    = fmaf(gv - mean, sc, bnbf[k]);
            v = v > 0.f ? v : 0.f;
            val = v + hv;
        } else {
            val = pert[b * 9 + (k - 128)];
        }
        sm[i] = val;
    }
    __syncthreads();
    int jl = t & 15;
    int j  = blockIdx.x * 16 + jl;
    int b0 = (t >> 4) * 4;
    float acc[4];
    float bias = r1b[j];
    acc[0] = acc[1] = acc[2] = acc[3] = bias;
    for (int k = 0; k < 137; ++k) {
        float w = r1W[k * 256 + j];
        #pragma unroll
        for (int i = 0; i < 4; ++i) acc[i] = fmaf(sm[(b0 + i) * 137 + k], w, acc[i]);
    }
    #pragma unroll
    for (int i = 0; i < 4; ++i) sc1[(b0 + i) * 16 + jl] = acc[i];
    __syncthreads();
    if (t < 16) {
        float s = 0.f, sq = 0.f;
        for (int b = 0; b < 64; ++b) { float v = sc1[b * 16 + t]; s += v; sq = fmaf(v, v, sq); }
        float mean = s * (1.f / 64.f), var = sq * (1.f / 64.f) - mean * mean;
        int jj = blockIdx.x * 16 + t;
        float sc = bn1g[jj] * rsqrtf(var + BN_EPS);
        sscale[t] = sc;
        sbeta[t]  = bn1b[jj] - mean * sc;
    }
    __syncthreads();
    float sc = sscale[jl], be = sbeta[jl];
    #pragma unroll
    for (int i = 0; i < 4; ++i) {
        float v = fmaf(acc[i], sc, be);
        c1[(b0 + i) * 256 + j] = v > 0.f ? v : 0.f;
    }
}

// ---------------- MLP stage 2 ----------------
__global__ __launch_bounds__(256) void k_mlp2(const float* __restrict__ c1,
                                              const float* __restrict__ r2W, const float* __restrict__ r2b,
                                              const float* __restrict__ bn2g, const float* __restrict__ bn2b,
                                              float* __restrict__ c2) {
    __shared__ float sm[64 * 256];
    __shared__ float sc2[64 * 16];
    __shared__ float sscale[16], sbeta[16];
    int t = threadIdx.x;
    for (int i = t; i < 64 * 64; i += 256) *(float4*)&sm[i * 4] = *(const float4*)&c1[i * 4];
    __syncthreads();
    int jl = t & 15;
    int j  = blockIdx.x * 16 + jl;
    int b0 = (t >> 4) * 4;
    float acc[4];
    float bias = r2b[j];
    acc[0] = acc[1] = acc[2] = acc[3] = bias;
    for (int k = 0; k < 256; ++k) {
        float w = r2W[k * 128 + j];
        #pragma unroll
        for (int i = 0; i < 4; ++i) acc[i] = fmaf(sm[(b0 + i) * 256 + k], w, acc[i]);
    }
    #pragma unroll
    for (int i = 0; i < 4; ++i) sc2[(b0 + i) * 16 + jl] = acc[i];
    __syncthreads();
    if (t < 16) {
        float s = 0.f, sq = 0.f;
        for (int b = 0; b < 64; ++b) { float v = sc2[b * 16 + t]; s += v; sq = fmaf(v, v, sq); }
        float mean = s * (1.f / 64.f), var = sq * (1.f / 64.f) - mean * mean;
        int jj = blockIdx.x * 16 + t;
        float sc = bn2g[jj] * rsqrtf(var + BN_EPS);
        sscale[t] = sc;
        sbeta[t]  = bn2b[jj] - mean * sc;
    }
    __syncthreads();
    float sc = sscale[jl], be = sbeta[jl];
    #pragma unroll
    for (int i = 0; i < 4; ++i) {
        float v = fmaf(acc[i], sc, be);
        c2[(b0 + i) * 128 + j] = v > 0.f ? v : 0.f;
    }
}

// ---------------- MLP stage 3 ----------------
__global__ __launch_bounds__(256) void k_mlp3(const float* __restrict__ c2,
                                              const float* __restrict__ r3W, const float* __restrict__ r3b,
                                              const float* __restrict__ clsW, const float* __restrict__ clsb,
                                              const float* __restrict__ regW, const float* __restrict__ regb,
                                              float* __restrict__ out) {
    __shared__ float sm[64 * 128];
    __shared__ float sc3[64 * 64];
    int t = threadIdx.x;
    for (int i = t; i < 64 * 32; i += 256) *(float4*)&sm[i * 4] = *(const float4*)&c2[i * 4];
    __syncthreads();
    {
        int j = t & 63, bb = t >> 6;
        float acc[16];
        float bias = r3b[j];
        #pragma unroll
        for (int i = 0; i < 16; ++i) acc[i] = bias;
        for (int k = 0; k < 128; ++k) {
            float w = r3W[k * 64 + j];
            #pragma unroll
            for (int i = 0; i < 16; ++i) acc[i] = fmaf(sm[(bb + 4 * i) * 128 + k], w, acc[i]);
        }
        #pragma unroll
        for (int i = 0; i < 16; ++i) { float v = acc[i]; sc3[(bb + 4 * i) * 64 + j] = v > 0.f ? v : 0.f; }
    }
    __syncthreads();
    if (t < 128) {
        int b = t >> 1, which = t & 1;
        const float* W = which ? regW : clsW;
        float acc = which ? regb[0] : clsb[0];
        for (int k = 0; k < 64; ++k) acc = fmaf(sc3[b * 64 + k], W[k], acc);
        out[b * 2 + which] = acc;
    }
}

extern "C" void kernel_launch(void* const* d_in, const int* in_sizes, int n_in,
                              void* d_out, int out_size, void* d_ws, size_t ws_size,
                              hipStream_t stream) {
    const float* x    = (const float*)d_in[0];
    const float* ea   = (const float*)d_in[1];
    const int*   ei   = (const int*)d_in[2];
    const int*   mi   = (const int*)d_in[3];
    const float* pert = (const float*)d_in[4];
    const float* npW  = (const float*)d_in[5];
    const float* npB  = (const float*)d_in[6];
    const float* epW  = (const float*)d_in[7];
    const float* epB  = (const float*)d_in[8];
    const float* Wl   = (const float*)d_in[9];
    const float* bl   = (const float*)d_in[10];
    const float* Wr   = (const float*)d_in[11];
    const float* br   = (const float*)d_in[12];
    const float* We   = (const float*)d_in[13];
    const float* att  = (const float*)d_in[14];
    const float* gb   = (const float*)d_in[15];
    const float* bng  = (const float*)d_in[16];
    const float* bnb  = (const float*)d_in[17];
    const float* r1W  = (const float*)d_in[18];
    const float* r1b  = (const float*)d_in[19];
    const float* bn1g = (const float*)d_in[20];
    const float* bn1b = (const float*)d_in[21];
    const float* r2W  = (const float*)d_in[22];
    const float* r2b  = (const float*)d_in[23];
    const float* bn2g = (const float*)d_in[24];
    const float* bn2b = (const float*)d_in[25];
    const float* r3W  = (const float*)d_in[26];
    const float* r3b  = (const float*)d_in[27];
    const float* clsW = (const float*)d_in[28];
    const float* clsb = (const float*)d_in[29];
    const float* regW = (const float*)d_in[30];
    const float* regb = (const float*)d_in[31];
    float* out = (float*)d_out;

    float* ws = (float*)d_ws;
    int*   cnt      = (int*)(ws + OFF_CNT);
    int*   fill     = (int*)(ws + OFF_FILL);
    float* bnstats  = ws + OFF_BNSTATS;
    int*   rowstart = (int*)(ws + OFF_ROWSTART);
    float* we3web   = ws + OFF_WE3;
    float* h        = ws + OFF_H;
    unsigned short* xlb = (unsigned short*)(ws + OFF_XLB);
    float* xr       = ws + OFF_XR;
    float* g        = ws + OFF_G;
    float4* csr     = (float4*)(ws + OFF_CSR);
    float* c1       = ws + OFF_C1;
    float* c2       = ws + OFF_C2;

    hipMemsetAsync(ws, 0, ZERO_ELEMS * sizeof(float), stream);

    k_prep_we3<<<6, 256, 0, stream>>>(epW, epB, We, we3web);
    k_hist<<<(NE + 255) / 256, 256, 0, stream>>>(ei, cnt);
    k_scan<<<1, 1024, 0, stream>>>(cnt, rowstart);
    k_scatter<<<(NE + 255) / 256, 256, 0, stream>>>(ei, ea, rowstart, fill, csr);
    k_node_proj<<<(NN + 15) / 16, 256, 0, stream>>>(x, npW, npB, h);

    const int GEMM_BLOCKS = (NN + 63) / 64;
    for (int l = 0; l < NL; ++l) {
        if (l == 0) {
            k_gemm<<<GEMM_BLOCKS, 256, 0, stream>>>(h, nullptr, nullptr, nullptr, nullptr, h,
                                                    Wl + l * HID * HID, bl + l * HID,
                                                    Wr + l * HID * HID, br + l * HID, xlb, xr, 0);
        } else {
            k_gemm<<<GEMM_BLOCKS, 256, 0, stream>>>(h, g, bnstats + (l - 1) * 256,
                                                    bng + (l - 1) * 128, bnb + (l - 1) * 128, h,
                                                    Wl + l * HID * HID, bl + l * HID,
                                                    Wr + l * HID * HID, br + l * HID, xlb, xr, 1);
        }
        k_gat<<<(NN + 3) / 4, 256, 0, stream>>>(xlb, xr, csr, rowstart, cnt,
                                                we3web + l * 512, att + l * 128, gb + l * 128, g);
        k_bn_stats<<<512, 128, 0, stream>>>(g, bnstats + l * 256);
    }

    k_mlp1<<<16, 256, 0, stream>>>(g, h, bnstats + 2 * 256, bng + 2 * 128, bnb + 2 * 128,
                                   mi, pert, r1W, r1b, bn1g, bn1b, c1);
    k_mlp2<<<8, 256, 0, stream>>>(c1, r2W, r2b, bn2g, bn2b, c2);
    k_mlp3<<<1, 256, 0, stream>>>(c2, r3W, r3b, clsW, clsb, regW, regb, out);
    (void)in_sizes; (void)n_in; (void)out_size; (void)ws_size;
}